// Round 2
// baseline (184.952 us; speedup 1.0000x reference)
//
#include <hip/hip_runtime.h>
#include <math.h>

#define BS_     64
#define NUM_KP_ 17
#define A_      8400
#define GRID_   80                   // IMAGE_SIZE / STRIDES[0] = 640/8
#define NCH_    (3 * NUM_KP_)        // 51
#define NROWS_  (BS_ * NUM_KP_)      // 1088
#define NCONF_  ((float)(BS_ * NUM_KP_ * A_))  // 9139200

#define LN2_        0.69314718055994530942f
#define CLAMP_LOG2_ (-144.26950408889634f)     // -100 / ln2

#if defined(__has_builtin)
#  if __has_builtin(__builtin_amdgcn_logf)
#    define FAST_LOG2(x) __builtin_amdgcn_logf(x)
#  else
#    define FAST_LOG2(x) __log2f(x)
#  endif
#else
#  define FAST_LOG2(x) __log2f(x)
#endif

// ws layout: ws[0]=conf log-sum (f32), ws[1]=xy sq-err sum (f32), ws[2]=arrival counter (u32)
__global__ __launch_bounds__(256) void yolo_kploss_main(
    const float* __restrict__ out,   // (BS, 51, 8400)
    const float* __restrict__ gt,    // (BS, 17, 2)
    const int*   __restrict__ visv,  // (BS, 17)
    float*       __restrict__ ws,
    float*       __restrict__ result)
{
    const int row = blockIdx.x;              // 0 .. 1087
    const int b   = row / NUM_KP_;
    const int k   = row - b * NUM_KP_;
    const int tid = threadIdx.x;

    const float* conf_row = out + ((size_t)b * NCH_ + 3 * k + 2) * A_;

    // Sum of clamp(log2(1-c), -144.27) over this row; scaled by ln2 at the end.
    float l2sum = 0.0f;

    const float4* c4 = (const float4*)conf_row;   // 2100 float4, 16B-aligned
    for (int i = tid; i < A_ / 4; i += 256) {
        float4 v = c4[i];
        l2sum += fmaxf(FAST_LOG2(1.0f - v.x), CLAMP_LOG2_);
        l2sum += fmaxf(FAST_LOG2(1.0f - v.y), CLAMP_LOG2_);
        l2sum += fmaxf(FAST_LOG2(1.0f - v.z), CLAMP_LOG2_);
        l2sum += fmaxf(FAST_LOG2(1.0f - v.w), CLAMP_LOG2_);
    }

    float conf_part = l2sum * LN2_;
    float xy_part   = 0.0f;

    if (tid == 0) {
        const float gx = gt[(b * NUM_KP_ + k) * 2 + 0];
        const float gy = gt[(b * NUM_KP_ + k) * 2 + 1];
        const int   vv = visv[b * NUM_KP_ + k];
        if (vv == 1) {
            const int bx  = (int)floorf(gx * 0.125f);
            const int by  = (int)floorf(gy * 0.125f);
            const int idx = by * GRID_ + bx;        // < 6400 < 8400
            const float xg = out[((size_t)b * NCH_ + 3 * k + 0) * A_ + idx];
            const float yg = out[((size_t)b * NCH_ + 3 * k + 1) * A_ + idx];
            const float c  = conf_row[idx];
            xy_part = (xg - gx) * (xg - gx) + (yg - gy) * (yg - gy);
            const float logp   = fmaxf(LN2_ * FAST_LOG2(c),        -100.0f);
            const float log1mp = fmaxf(LN2_ * FAST_LOG2(1.0f - c), -100.0f);
            conf_part += (logp - log1mp);   // masked position: logp replaces log1mp
        }
    }

    // Block reduce conf_part: wave64 shuffle, then LDS across the 4 waves.
    #pragma unroll
    for (int off = 32; off > 0; off >>= 1)
        conf_part += __shfl_down(conf_part, off, 64);

    __shared__ float s[4];
    const int wave = tid >> 6;
    const int lane = tid & 63;
    if (lane == 0) s[wave] = conf_part;
    __syncthreads();

    if (tid == 0) {
        const float total = s[0] + s[1] + s[2] + s[3];
        atomicAdd(&ws[0], total);
        if (xy_part != 0.0f) atomicAdd(&ws[1], xy_part);
        __threadfence();                       // value adds visible before ticket
        unsigned* cnt = (unsigned*)(ws + 2);
        const unsigned ticket = atomicAdd(cnt, 1u);
        if (ticket == NROWS_ - 1) {            // last block to finish
            const float c_sum  = atomicAdd(&ws[0], 0.0f);  // L2-coherent read
            const float xy_sum = atomicAdd(&ws[1], 0.0f);
            result[0] = -c_sum / NCONF_ + xy_sum / (float)BS_;
        }
    }
}

extern "C" void kernel_launch(void* const* d_in, const int* in_sizes, int n_in,
                              void* d_out, int out_size, void* d_ws, size_t ws_size,
                              hipStream_t stream) {
    const float* out_t = (const float*)d_in[0];   // (64, 51, 8400) fp32
    // d_in[1] = target, unused by the reference math
    const float* gt    = (const float*)d_in[2];   // (64, 17, 2) fp32
    const int*   vis   = (const int*)d_in[3];     // (64, 17) int32

    float* ws = (float*)d_ws;
    hipMemsetAsync(ws, 0, 3 * sizeof(float), stream);

    yolo_kploss_main<<<NROWS_, 256, 0, stream>>>(out_t, gt, vis, ws, (float*)d_out);
}